// Round 9
// baseline (6289.768 us; speedup 1.0000x reference)
//
#include <hip/hip_runtime.h>
#include <math.h>

namespace {
constexpr int   Bb    = 16;
constexpr int   Nn    = 2048;
constexpr int   Mm    = 2048;
constexpr float EPSf  = 0.005f;
constexpr float TOLf  = 1e-3f;
constexpr int   MAXIT = 100;
constexpr float LN2f  = 0.69314718055994531f;
constexpr float C2f   = 288.53900817779268f;   // log2(e)/EPS
constexpr int   BLOCK = 256;
constexpr int   RW    = 4;                     // rows per wave (registers)
constexpr int   RPB   = 16;                    // rows per block (4 waves * RW)
constexpr int   SUBS  = Nn / RPB;              // 128 blocks per batch
constexpr int   GRID  = Bb * SUBS;             // 2048
constexpr int   SLOTSTRIDE = 16;               // dwords per (it,batch) slot line
}

__device__ __forceinline__ float ex2(float x) { return __builtin_amdgcn_exp2f(x); }

// one-time: [B][N][3] scalar coords -> [B][N] float4 (x,y,z, pot*C2f=0)
__global__ __launch_bounds__(BLOCK) void pack_pts(const float* __restrict__ p,
                                                  float4* __restrict__ pk, int npts) {
  int i = blockIdx.x * BLOCK + threadIdx.x;
  if (i < npts) pk[i] = make_float4(p[3 * i], p[3 * i + 1], p[3 * i + 2], 0.0f);
}

__global__ __launch_bounds__(BLOCK) void init_ws(unsigned* w, int nwords) {
  int i = blockIdx.x * BLOCK + threadIdx.x;
  if (i < nwords) w[i] = 0u;
}

// One Sinkhorn half-step, LDS-free (column cloud is L1/L2-resident; pot fused
// in .w). Convergence preamble: 32 LANES load the 32 slot dwords once per
// block + LDS broadcast -- R8 had every thread load all 32 (16.7M same-line
// L2 hits per dispatch = serialized burst at dispatch start).
__global__ __launch_bounds__(BLOCK, 8) void sink_pass(
    const float4* __restrict__ pkc,   // column cloud, pot*C2f fused in .w
    float4* __restrict__ pkr,         // row cloud; we write .w = pnew*C2f
    float* __restrict__ potr,         // plain potential array (deltas + final)
    unsigned* slotbase, const unsigned* chk, int uvsel) {
  __shared__ float red[4];
  __shared__ float convm;
  const int tid = threadIdx.x, lane = tid & 63, wid = tid >> 6;
  if (chk != nullptr) {
    if (tid < 32) {
      float v = __uint_as_float(__hip_atomic_load(
          chk + (tid >> 1) * SLOTSTRIDE + (tid & 1),
          __ATOMIC_RELAXED, __HIP_MEMORY_SCOPE_AGENT));
      #pragma unroll
      for (int off = 16; off >= 1; off >>= 1) v = fmaxf(v, __shfl_xor(v, off));
      if (tid == 0) convm = v;
    }
    __syncthreads();
    if (convm < TOLf) return;                   // converged: freeze (uniform)
  }
  const int b = blockIdx.x >> 7, sub = blockIdx.x & 127;
  const float4* PC = pkc + b * Mm;
  float4*       PRq = pkr + b * Nn;
  float*        QR  = potr + b * Nn;

  const int base_n = sub * RPB + wid * RW;
  float qx[RW], qy[RW], qz[RW], rm[RW], ss[RW];
  #pragma unroll
  for (int r = 0; r < RW; ++r) {
    float4 q = PRq[base_n + r];                 // same addr across wave: broadcast
    qx[r] = q.x; qy[r] = q.y; qz[r] = q.z;
    rm[r] = -3.0e38f; ss[r] = 0.0f;
  }

  const float4* p = PC + lane;
  #pragma unroll 2
  for (int j = 0; j < 32; j += 4) {             // 8-pt straight-line after unroll
    float4 f0 = p[(j + 0) * 64];
    float4 f1 = p[(j + 1) * 64];
    float4 f2 = p[(j + 2) * 64];
    float4 f3 = p[(j + 3) * 64];
    #pragma unroll
    for (int r = 0; r < RW; ++r) {
      float dx0 = f0.x - qx[r], dy0 = f0.y - qy[r], dz0 = f0.z - qz[r];
      float dx1 = f1.x - qx[r], dy1 = f1.y - qy[r], dz1 = f1.z - qz[r];
      float dx2 = f2.x - qx[r], dy2 = f2.y - qy[r], dz2 = f2.z - qz[r];
      float dx3 = f3.x - qx[r], dy3 = f3.y - qy[r], dz3 = f3.z - qz[r];
      float d0 = fmaf(dz0, dz0, fmaf(dy0, dy0, dx0 * dx0));
      float d1 = fmaf(dz1, dz1, fmaf(dy1, dy1, dx1 * dx1));
      float d2 = fmaf(dz2, dz2, fmaf(dy2, dy2, dx2 * dx2));
      float d3 = fmaf(dz3, dz3, fmaf(dy3, dy3, dx3 * dx3));
      float y0 = fmaf(__builtin_amdgcn_sqrtf(d0), -C2f, f0.w);
      float y1 = fmaf(__builtin_amdgcn_sqrtf(d1), -C2f, f1.w);
      float y2 = fmaf(__builtin_amdgcn_sqrtf(d2), -C2f, f2.w);
      float y3 = fmaf(__builtin_amdgcn_sqrtf(d3), -C2f, f3.w);
      float pm = fmaxf(fmaxf(y0, y1), fmaxf(y2, y3));
      float nm = fmaxf(rm[r], pm);
      float e  = (ex2(y0 - nm) + ex2(y1 - nm)) + (ex2(y2 - nm) + ex2(y3 - nm));
      ss[r] = fmaf(ss[r], ex2(rm[r] - nm), e);
      rm[r] = nm;
    }
  }

  const float log_ab = logf(1.0f / 2048.0f + 1e-8f);   // constant-folded
  float* PRw = (float*)(PRq);
  float dmax = 0.0f;
  #pragma unroll
  for (int r = 0; r < RW; ++r) {
    // two-phase merge: max-reduce, single rescale exp2, sum-reduce
    float gm = rm[r];
    #pragma unroll
    for (int off = 1; off < 64; off <<= 1) gm = fmaxf(gm, __shfl_xor(gm, off));
    float sc = ss[r] * ex2(rm[r] - gm);
    #pragma unroll
    for (int off = 1; off < 64; off <<= 1) sc += __shfl_xor(sc, off);
    float lse = (gm + __builtin_amdgcn_logf(sc)) * LN2f;   // v_log_f32 is log2
    float pnew = EPSf * (log_ab - lse);
    if (lane == 0) {
      int n = base_n + r;
      dmax = fmaxf(dmax, fabsf(pnew - QR[n]));
      QR[n] = pnew;
      PRw[4 * n + 3] = pnew * C2f;              // fuse pot for consumer pass
    }
  }
  if (lane == 0) red[wid] = dmax;
  __syncthreads();
  if (tid == 0) {
    float m = fmaxf(fmaxf(red[0], red[1]), fmaxf(red[2], red[3]));
    atomicMax(slotbase + b * SLOTSTRIDE + uvsel, __float_as_uint(m));
  }
}

// part[blk] = block-partial of sum_{n,m} exp((u+v-dist)/eps) * dist
__global__ __launch_bounds__(BLOCK, 8) void final_emd(
    const float4* __restrict__ pk1,   // row cloud coords (w ignored)
    const float4* __restrict__ pk2,   // column cloud, V*C2f fused in .w
    const float* __restrict__ U, float* __restrict__ part) {
  __shared__ float red[4];
  const int tid = threadIdx.x, lane = tid & 63, wid = tid >> 6;
  const int b = blockIdx.x >> 7, sub = blockIdx.x & 127;
  const float4* PC = pk2 + b * Mm;
  const float4* PRq = pk1 + b * Nn;

  const int base_n = sub * RPB + wid * RW;
  float qx[RW], qy[RW], qz[RW], uc[RW], ac[RW];
  #pragma unroll
  for (int r = 0; r < RW; ++r) {
    float4 q = PRq[base_n + r];
    qx[r] = q.x; qy[r] = q.y; qz[r] = q.z;
    uc[r] = U[b * Nn + base_n + r] * C2f;
    ac[r] = 0.0f;
  }

  const float4* p = PC + lane;
  #pragma unroll 2
  for (int j = 0; j < 32; j += 4) {
    float4 f0 = p[(j + 0) * 64];
    float4 f1 = p[(j + 1) * 64];
    float4 f2 = p[(j + 2) * 64];
    float4 f3 = p[(j + 3) * 64];
    #pragma unroll
    for (int r = 0; r < RW; ++r) {
      float dx0 = f0.x - qx[r], dy0 = f0.y - qy[r], dz0 = f0.z - qz[r];
      float dx1 = f1.x - qx[r], dy1 = f1.y - qy[r], dz1 = f1.z - qz[r];
      float dx2 = f2.x - qx[r], dy2 = f2.y - qy[r], dz2 = f2.z - qz[r];
      float dx3 = f3.x - qx[r], dy3 = f3.y - qy[r], dz3 = f3.z - qz[r];
      float e0 = fmaf(dz0, dz0, fmaf(dy0, dy0, dx0 * dx0));
      float e1 = fmaf(dz1, dz1, fmaf(dy1, dy1, dx1 * dx1));
      float e2 = fmaf(dz2, dz2, fmaf(dy2, dy2, dx2 * dx2));
      float e3 = fmaf(dz3, dz3, fmaf(dy3, dy3, dx3 * dx3));
      float t0 = __builtin_amdgcn_sqrtf(e0);
      float t1 = __builtin_amdgcn_sqrtf(e1);
      float t2 = __builtin_amdgcn_sqrtf(e2);
      float t3 = __builtin_amdgcn_sqrtf(e3);
      ac[r] = fmaf(ex2(fmaf(t0, -C2f, f0.w) + uc[r]), t0, ac[r]);
      ac[r] = fmaf(ex2(fmaf(t1, -C2f, f1.w) + uc[r]), t1, ac[r]);
      ac[r] = fmaf(ex2(fmaf(t2, -C2f, f2.w) + uc[r]), t2, ac[r]);
      ac[r] = fmaf(ex2(fmaf(t3, -C2f, f3.w) + uc[r]), t3, ac[r]);
    }
  }
  float acc = 0.0f;
  #pragma unroll
  for (int r = 0; r < RW; ++r) acc += ac[r];
  #pragma unroll
  for (int off = 1; off < 64; off <<= 1) acc += __shfl_xor(acc, off);
  if (lane == 0) red[wid] = acc;
  __syncthreads();
  if (tid == 0) part[blockIdx.x] = (red[0] + red[1]) + (red[2] + red[3]);
}

__global__ __launch_bounds__(BLOCK) void write_out(const float* __restrict__ part,
                                                   float* __restrict__ out) {
  __shared__ double sd[BLOCK];
  int t = threadIdx.x;
  double s = 0.0;
  for (int i = t; i < GRID; i += BLOCK) s += (double)part[i];
  sd[t] = s;
  __syncthreads();
  for (int k = BLOCK / 2; k > 0; k >>= 1) {
    if (t < k) sd[t] += sd[t + k];
    __syncthreads();
  }
  if (t == 0) out[0] = (float)(sd[0] / (double)Bb);
}

extern "C" void kernel_launch(void* const* d_in, const int* in_sizes, int n_in,
                              void* d_out, int out_size, void* d_ws, size_t ws_size,
                              hipStream_t stream) {
  (void)in_sizes; (void)n_in; (void)out_size; (void)ws_size;
  const float* p1 = (const float*)d_in[0];
  const float* p2 = (const float*)d_in[1];
  char* ws = (char*)d_ws;
  float4*   pk1   = (float4*)(ws + 0);          // 16*2048*16B = 524288
  float4*   pk2   = (float4*)(ws + 524288);     // 524288
  float*    U     = (float*)(ws + 1048576);     // 131072
  float*    V     = (float*)(ws + 1179648);     // 131072
  unsigned* slots = (unsigned*)(ws + 1310720);  // 100*16*64B = 102400
  float*    part  = (float*)(ws + 1413120);     // 2048*4 = 8192

  const int npts = Bb * Nn;                     // 32768 per cloud
  pack_pts<<<(npts + BLOCK - 1) / BLOCK, BLOCK, 0, stream>>>(p1, pk1, npts);
  pack_pts<<<(npts + BLOCK - 1) / BLOCK, BLOCK, 0, stream>>>(p2, pk2, npts);
  const int nwords = (2 * Bb * Nn * 4 + MAXIT * Bb * SLOTSTRIDE * 4) / 4;
  init_ws<<<(nwords + BLOCK - 1) / BLOCK, BLOCK, 0, stream>>>((unsigned*)(ws + 1048576), nwords);

  for (int it = 0; it < MAXIT; ++it) {
    unsigned*       sl  = slots + it * Bb * SLOTSTRIDE;
    const unsigned* chk = it ? slots + (it - 1) * Bb * SLOTSTRIDE : nullptr;
    // u-update: rows = pk1, cols = pk2 (V fused), writes U + pk1.w
    sink_pass<<<GRID, BLOCK, 0, stream>>>(pk2, pk1, U, sl, chk, 0);
    // v-update: rows = pk2, cols = pk1 (U fused), writes V + pk2.w
    sink_pass<<<GRID, BLOCK, 0, stream>>>(pk1, pk2, V, sl, chk, 1);
  }

  final_emd<<<GRID, BLOCK, 0, stream>>>(pk1, pk2, U, part);
  write_out<<<1, BLOCK, 0, stream>>>(part, (float*)d_out);
}

// Round 10
// 5873.790 us; speedup vs baseline: 1.0708x; 1.0708x over previous
//
#include <hip/hip_runtime.h>
#include <math.h>

namespace {
constexpr int   Bb    = 16;
constexpr int   Nn    = 2048;
constexpr int   Mm    = 2048;
constexpr float EPSf  = 0.005f;
constexpr float TOLf  = 1e-3f;
constexpr int   MAXIT = 100;
constexpr float LN2f  = 0.69314718055994531f;
constexpr float L2Ef  = 1.44269504088896340f;  // log2(e)
constexpr float C2f   = 288.53900817779268f;   // log2(e)/EPS
constexpr int   BLOCK = 256;
constexpr int   RW    = 4;                     // rows per wave (registers)
constexpr int   RPB   = 16;                    // rows per block (4 waves * RW)
constexpr int   SUBS  = Nn / RPB;              // 128 blocks per batch
constexpr int   GRID  = Bb * SUBS;             // 2048
constexpr int   SLOTSTRIDE = 16;               // dwords per (it,batch) slot line
}

__device__ __forceinline__ float ex2(float x) { return __builtin_amdgcn_exp2f(x); }

// one-time: [B][N][3] scalar coords -> [B][N] float4 (x,y,z, pot*C2f=0)
__global__ __launch_bounds__(BLOCK) void pack_pts(const float* __restrict__ p,
                                                  float4* __restrict__ pk, int npts) {
  int i = blockIdx.x * BLOCK + threadIdx.x;
  if (i < npts) pk[i] = make_float4(p[3 * i], p[3 * i + 1], p[3 * i + 2], 0.0f);
}

__global__ __launch_bounds__(BLOCK) void init_ws(unsigned* w, int nwords) {
  int i = blockIdx.x * BLOCK + threadIdx.x;
  if (i < nwords) w[i] = 0u;
}

__device__ __forceinline__ bool conv_check(const unsigned* chk, int tid, float* convm) {
  if (tid < 32) {
    float v = __uint_as_float(__hip_atomic_load(
        chk + (tid >> 1) * SLOTSTRIDE + (tid & 1),
        __ATOMIC_RELAXED, __HIP_MEMORY_SCOPE_AGENT));
    #pragma unroll
    for (int off = 16; off >= 1; off >>= 1) v = fmaxf(v, __shfl_xor(v, off));
    if (tid == 0) *convm = v;
  }
  __syncthreads();
  return *convm < TOLf;
}

// it=0 half-steps: online-max LSE (no prior potential to predict the shift).
__global__ __launch_bounds__(BLOCK, 8) void sink_pass(
    const float4* __restrict__ pkc, float4* __restrict__ pkr,
    float* __restrict__ potr, unsigned* slotbase, int uvsel) {
  __shared__ float red[4];
  const int tid = threadIdx.x, lane = tid & 63, wid = tid >> 6;
  const int b = blockIdx.x >> 7, sub = blockIdx.x & 127;
  const float4* PC = pkc + b * Mm;
  float4*       PRq = pkr + b * Nn;
  float*        QR  = potr + b * Nn;

  const int base_n = sub * RPB + wid * RW;
  float qx[RW], qy[RW], qz[RW], rm[RW], ss[RW];
  #pragma unroll
  for (int r = 0; r < RW; ++r) {
    float4 q = PRq[base_n + r];
    qx[r] = q.x; qy[r] = q.y; qz[r] = q.z;
    rm[r] = -3.0e38f; ss[r] = 0.0f;
  }

  const float4* p = PC + lane;
  #pragma unroll 2
  for (int j = 0; j < 32; j += 4) {
    float4 f0 = p[(j + 0) * 64];
    float4 f1 = p[(j + 1) * 64];
    float4 f2 = p[(j + 2) * 64];
    float4 f3 = p[(j + 3) * 64];
    #pragma unroll
    for (int r = 0; r < RW; ++r) {
      float dx0 = f0.x - qx[r], dy0 = f0.y - qy[r], dz0 = f0.z - qz[r];
      float dx1 = f1.x - qx[r], dy1 = f1.y - qy[r], dz1 = f1.z - qz[r];
      float dx2 = f2.x - qx[r], dy2 = f2.y - qy[r], dz2 = f2.z - qz[r];
      float dx3 = f3.x - qx[r], dy3 = f3.y - qy[r], dz3 = f3.z - qz[r];
      float d0 = fmaf(dz0, dz0, fmaf(dy0, dy0, dx0 * dx0));
      float d1 = fmaf(dz1, dz1, fmaf(dy1, dy1, dx1 * dx1));
      float d2 = fmaf(dz2, dz2, fmaf(dy2, dy2, dx2 * dx2));
      float d3 = fmaf(dz3, dz3, fmaf(dy3, dy3, dx3 * dx3));
      float y0 = fmaf(__builtin_amdgcn_sqrtf(d0), -C2f, f0.w);
      float y1 = fmaf(__builtin_amdgcn_sqrtf(d1), -C2f, f1.w);
      float y2 = fmaf(__builtin_amdgcn_sqrtf(d2), -C2f, f2.w);
      float y3 = fmaf(__builtin_amdgcn_sqrtf(d3), -C2f, f3.w);
      float pm = fmaxf(fmaxf(y0, y1), fmaxf(y2, y3));
      float nm = fmaxf(rm[r], pm);
      float e  = (ex2(y0 - nm) + ex2(y1 - nm)) + (ex2(y2 - nm) + ex2(y3 - nm));
      ss[r] = fmaf(ss[r], ex2(rm[r] - nm), e);
      rm[r] = nm;
    }
  }

  const float log_ab = logf(1.0f / 2048.0f + 1e-8f);
  float* PRw = (float*)(PRq);
  float dmax = 0.0f;
  #pragma unroll
  for (int r = 0; r < RW; ++r) {
    float gm = rm[r];
    #pragma unroll
    for (int off = 1; off < 64; off <<= 1) gm = fmaxf(gm, __shfl_xor(gm, off));
    float sc = ss[r] * ex2(rm[r] - gm);
    #pragma unroll
    for (int off = 1; off < 64; off <<= 1) sc += __shfl_xor(sc, off);
    float lse = (gm + __builtin_amdgcn_logf(sc)) * LN2f;
    float pnew = EPSf * (log_ab - lse);
    if (lane == 0) {
      int n = base_n + r;
      dmax = fmaxf(dmax, fabsf(pnew - QR[n]));
      QR[n] = pnew;
      PRw[4 * n + 3] = pnew * C2f;
    }
  }
  if (lane == 0) red[wid] = dmax;
  __syncthreads();
  if (tid == 0) {
    float m = fmaxf(fmaxf(red[0], red[1]), fmaxf(red[2], red[3]));
    atomicMax(slotbase + b * SLOTSTRIDE + uvsel, __float_as_uint(m));
  }
}

// it>=1 half-steps: fixed-shift LSE. K_r = previous iteration's base-2 LSE for
// this row, recovered exactly from u_prev: lse2_prev = (log_ab - u/EPS)*log2e.
// Potentials drift <= ~35 exponent units/iter << f32's ~100-unit safety band,
// so sum neither under- nor overflows. Kills the online-max serial chain:
// 9 VALU + 2 trans per eval, all independent.
__global__ __launch_bounds__(BLOCK, 8) void sink_fast(
    const float4* __restrict__ pkc, float4* __restrict__ pkr,
    float* __restrict__ potr, unsigned* slotbase, const unsigned* chk, int uvsel) {
  __shared__ float red[4];
  __shared__ float convm;
  const int tid = threadIdx.x, lane = tid & 63, wid = tid >> 6;
  if (conv_check(chk, tid, &convm)) return;     // frozen: slots stay 0 -> sticky
  const int b = blockIdx.x >> 7, sub = blockIdx.x & 127;
  const float4* PC = pkc + b * Mm;
  float4*       PRq = pkr + b * Nn;
  float*        QR  = potr + b * Nn;

  const float log_ab = logf(1.0f / 2048.0f + 1e-8f);
  const float log2ab = log_ab * L2Ef;

  const int base_n = sub * RPB + wid * RW;
  float qx[RW], qy[RW], qz[RW], K[RW], up[RW], s[RW];
  #pragma unroll
  for (int r = 0; r < RW; ++r) {
    float4 q = PRq[base_n + r];                 // wave-uniform: broadcast
    qx[r] = q.x; qy[r] = q.y; qz[r] = q.z;
    up[r] = QR[base_n + r];                     // u_prev
    K[r]  = log2ab - q.w;                       // q.w = u_prev*C2f -> lse2_prev
    s[r]  = 0.0f;
  }

  const float4* p = PC + lane;
  #pragma unroll 2
  for (int j = 0; j < 32; j += 4) {
    float4 f0 = p[(j + 0) * 64];
    float4 f1 = p[(j + 1) * 64];
    float4 f2 = p[(j + 2) * 64];
    float4 f3 = p[(j + 3) * 64];
    #pragma unroll
    for (int r = 0; r < RW; ++r) {
      float w0 = f0.w - K[r], w1 = f1.w - K[r], w2 = f2.w - K[r], w3 = f3.w - K[r];
      float dx0 = f0.x - qx[r], dy0 = f0.y - qy[r], dz0 = f0.z - qz[r];
      float dx1 = f1.x - qx[r], dy1 = f1.y - qy[r], dz1 = f1.z - qz[r];
      float dx2 = f2.x - qx[r], dy2 = f2.y - qy[r], dz2 = f2.z - qz[r];
      float dx3 = f3.x - qx[r], dy3 = f3.y - qy[r], dz3 = f3.z - qz[r];
      float d0 = fmaf(dz0, dz0, fmaf(dy0, dy0, dx0 * dx0));
      float d1 = fmaf(dz1, dz1, fmaf(dy1, dy1, dx1 * dx1));
      float d2 = fmaf(dz2, dz2, fmaf(dy2, dy2, dx2 * dx2));
      float d3 = fmaf(dz3, dz3, fmaf(dy3, dy3, dx3 * dx3));
      float e0 = ex2(fmaf(__builtin_amdgcn_sqrtf(d0), -C2f, w0));
      float e1 = ex2(fmaf(__builtin_amdgcn_sqrtf(d1), -C2f, w1));
      float e2 = ex2(fmaf(__builtin_amdgcn_sqrtf(d2), -C2f, w2));
      float e3 = ex2(fmaf(__builtin_amdgcn_sqrtf(d3), -C2f, w3));
      s[r] += (e0 + e1) + (e2 + e3);
    }
  }

  float* PRw = (float*)(PRq);
  float dmax = 0.0f;
  #pragma unroll
  for (int r = 0; r < RW; ++r) {
    float sv = s[r];
    #pragma unroll
    for (int off = 1; off < 64; off <<= 1) sv += __shfl_xor(sv, off);
    float lse = (K[r] + __builtin_amdgcn_logf(sv)) * LN2f;  // v_log_f32 = log2
    float pnew = EPSf * (log_ab - lse);
    if (lane == 0) {
      int n = base_n + r;
      dmax = fmaxf(dmax, fabsf(pnew - up[r]));
      QR[n] = pnew;
      PRw[4 * n + 3] = pnew * C2f;
    }
  }
  if (lane == 0) red[wid] = dmax;
  __syncthreads();
  if (tid == 0) {
    float m = fmaxf(fmaxf(red[0], red[1]), fmaxf(red[2], red[3]));
    atomicMax(slotbase + b * SLOTSTRIDE + uvsel, __float_as_uint(m));
  }
}

// part[blk] = block-partial of sum_{n,m} exp((u+v-dist)/eps) * dist
__global__ __launch_bounds__(BLOCK, 8) void final_emd(
    const float4* __restrict__ pk1, const float4* __restrict__ pk2,
    const float* __restrict__ U, float* __restrict__ part) {
  __shared__ float red[4];
  const int tid = threadIdx.x, lane = tid & 63, wid = tid >> 6;
  const int b = blockIdx.x >> 7, sub = blockIdx.x & 127;
  const float4* PC = pk2 + b * Mm;
  const float4* PRq = pk1 + b * Nn;

  const int base_n = sub * RPB + wid * RW;
  float qx[RW], qy[RW], qz[RW], uc[RW], ac[RW];
  #pragma unroll
  for (int r = 0; r < RW; ++r) {
    float4 q = PRq[base_n + r];
    qx[r] = q.x; qy[r] = q.y; qz[r] = q.z;
    uc[r] = U[b * Nn + base_n + r] * C2f;
    ac[r] = 0.0f;
  }

  const float4* p = PC + lane;
  #pragma unroll 2
  for (int j = 0; j < 32; j += 4) {
    float4 f0 = p[(j + 0) * 64];
    float4 f1 = p[(j + 1) * 64];
    float4 f2 = p[(j + 2) * 64];
    float4 f3 = p[(j + 3) * 64];
    #pragma unroll
    for (int r = 0; r < RW; ++r) {
      float dx0 = f0.x - qx[r], dy0 = f0.y - qy[r], dz0 = f0.z - qz[r];
      float dx1 = f1.x - qx[r], dy1 = f1.y - qy[r], dz1 = f1.z - qz[r];
      float dx2 = f2.x - qx[r], dy2 = f2.y - qy[r], dz2 = f2.z - qz[r];
      float dx3 = f3.x - qx[r], dy3 = f3.y - qy[r], dz3 = f3.z - qz[r];
      float e0 = fmaf(dz0, dz0, fmaf(dy0, dy0, dx0 * dx0));
      float e1 = fmaf(dz1, dz1, fmaf(dy1, dy1, dx1 * dx1));
      float e2 = fmaf(dz2, dz2, fmaf(dy2, dy2, dx2 * dx2));
      float e3 = fmaf(dz3, dz3, fmaf(dy3, dy3, dx3 * dx3));
      float t0 = __builtin_amdgcn_sqrtf(e0);
      float t1 = __builtin_amdgcn_sqrtf(e1);
      float t2 = __builtin_amdgcn_sqrtf(e2);
      float t3 = __builtin_amdgcn_sqrtf(e3);
      ac[r] = fmaf(ex2(fmaf(t0, -C2f, f0.w) + uc[r]), t0, ac[r]);
      ac[r] = fmaf(ex2(fmaf(t1, -C2f, f1.w) + uc[r]), t1, ac[r]);
      ac[r] = fmaf(ex2(fmaf(t2, -C2f, f2.w) + uc[r]), t2, ac[r]);
      ac[r] = fmaf(ex2(fmaf(t3, -C2f, f3.w) + uc[r]), t3, ac[r]);
    }
  }
  float acc = 0.0f;
  #pragma unroll
  for (int r = 0; r < RW; ++r) acc += ac[r];
  #pragma unroll
  for (int off = 1; off < 64; off <<= 1) acc += __shfl_xor(acc, off);
  if (lane == 0) red[wid] = acc;
  __syncthreads();
  if (tid == 0) part[blockIdx.x] = (red[0] + red[1]) + (red[2] + red[3]);
}

__global__ __launch_bounds__(BLOCK) void write_out(const float* __restrict__ part,
                                                   float* __restrict__ out) {
  __shared__ double sd[BLOCK];
  int t = threadIdx.x;
  double s = 0.0;
  for (int i = t; i < GRID; i += BLOCK) s += (double)part[i];
  sd[t] = s;
  __syncthreads();
  for (int k = BLOCK / 2; k > 0; k >>= 1) {
    if (t < k) sd[t] += sd[t + k];
    __syncthreads();
  }
  if (t == 0) out[0] = (float)(sd[0] / (double)Bb);
}

extern "C" void kernel_launch(void* const* d_in, const int* in_sizes, int n_in,
                              void* d_out, int out_size, void* d_ws, size_t ws_size,
                              hipStream_t stream) {
  (void)in_sizes; (void)n_in; (void)out_size; (void)ws_size;
  const float* p1 = (const float*)d_in[0];
  const float* p2 = (const float*)d_in[1];
  char* ws = (char*)d_ws;
  float4*   pk1   = (float4*)(ws + 0);          // 16*2048*16B = 524288
  float4*   pk2   = (float4*)(ws + 524288);     // 524288
  float*    U     = (float*)(ws + 1048576);     // 131072
  float*    V     = (float*)(ws + 1179648);     // 131072
  unsigned* slots = (unsigned*)(ws + 1310720);  // 100*16*64B = 102400
  float*    part  = (float*)(ws + 1413120);     // 2048*4 = 8192

  const int npts = Bb * Nn;                     // 32768 per cloud
  pack_pts<<<(npts + BLOCK - 1) / BLOCK, BLOCK, 0, stream>>>(p1, pk1, npts);
  pack_pts<<<(npts + BLOCK - 1) / BLOCK, BLOCK, 0, stream>>>(p2, pk2, npts);
  const int nwords = (2 * Bb * Nn * 4 + MAXIT * Bb * SLOTSTRIDE * 4) / 4;
  init_ws<<<(nwords + BLOCK - 1) / BLOCK, BLOCK, 0, stream>>>((unsigned*)(ws + 1048576), nwords);

  // it = 0: online-max (no shift estimate exists yet)
  sink_pass<<<GRID, BLOCK, 0, stream>>>(pk2, pk1, U, slots, 0);
  sink_pass<<<GRID, BLOCK, 0, stream>>>(pk1, pk2, V, slots, 1);
  // it = 1..99: fixed-shift fast path
  for (int it = 1; it < MAXIT; ++it) {
    unsigned*       sl  = slots + it * Bb * SLOTSTRIDE;
    const unsigned* chk = slots + (it - 1) * Bb * SLOTSTRIDE;
    sink_fast<<<GRID, BLOCK, 0, stream>>>(pk2, pk1, U, sl, chk, 0);
    sink_fast<<<GRID, BLOCK, 0, stream>>>(pk1, pk2, V, sl, chk, 1);
  }

  final_emd<<<GRID, BLOCK, 0, stream>>>(pk1, pk2, U, part);
  write_out<<<1, BLOCK, 0, stream>>>(part, (float*)d_out);
}

// Round 11
// 5186.216 us; speedup vs baseline: 1.2128x; 1.1326x over previous
//
#include <hip/hip_runtime.h>
#include <math.h>

namespace {
constexpr int   Bb    = 16;
constexpr int   Nn    = 2048;
constexpr int   Mm    = 2048;
constexpr float EPSf  = 0.005f;
constexpr float TOLf  = 1e-3f;
constexpr int   MAXIT = 100;
constexpr float LN2f  = 0.69314718055994531f;
constexpr float L2Ef  = 1.44269504088896340f;  // log2(e)
constexpr float C2f   = 288.53900817779268f;   // log2(e)/EPS
constexpr int   BLOCK = 256;
constexpr int   RW    = 4;                     // rows per wave
constexpr int   RPB   = 16;                    // rows per block
constexpr int   SUBS  = Nn / RPB;              // 128 blocks per batch
constexpr int   GRID  = Bb * SUBS;             // 2048
constexpr int   SLOTSTRIDE = 16;
constexpr int   NCH   = 32;                    // chunks (64 pts) per batch
}

__device__ __forceinline__ float ex2(float x) { return __builtin_amdgcn_exp2f(x); }

__global__ __launch_bounds__(BLOCK) void pack_pts(const float* __restrict__ p,
                                                  float4* __restrict__ pk, int npts) {
  int i = blockIdx.x * BLOCK + threadIdx.x;
  if (i < npts) pk[i] = make_float4(p[3 * i], p[3 * i + 1], p[3 * i + 2], 0.0f);
}

__global__ __launch_bounds__(BLOCK) void init_ws(unsigned* w, int nwords) {
  int i = blockIdx.x * BLOCK + threadIdx.x;
  if (i < nwords) w[i] = 0u;
}

// per-(cloud,batch) bounding box
__global__ __launch_bounds__(BLOCK) void bbox_k(const float4* __restrict__ pk1,
                                                const float4* __restrict__ pk2,
                                                float4* __restrict__ bbox) {
  __shared__ float4 smin[BLOCK], smax[BLOCK];
  const int cb = blockIdx.x;                    // cloud*16 + batch
  const float4* p = (cb < 16 ? pk1 : pk2) + (cb & 15) * Nn;
  float4 mn = make_float4(3e38f, 3e38f, 3e38f, 0), mx = make_float4(-3e38f, -3e38f, -3e38f, 0);
  for (int i = threadIdx.x; i < Nn; i += BLOCK) {
    float4 v = p[i];
    mn.x = fminf(mn.x, v.x); mn.y = fminf(mn.y, v.y); mn.z = fminf(mn.z, v.z);
    mx.x = fmaxf(mx.x, v.x); mx.y = fmaxf(mx.y, v.y); mx.z = fmaxf(mx.z, v.z);
  }
  smin[threadIdx.x] = mn; smax[threadIdx.x] = mx;
  __syncthreads();
  for (int k = BLOCK / 2; k > 0; k >>= 1) {
    if (threadIdx.x < k) {
      float4 a = smin[threadIdx.x], c = smin[threadIdx.x + k];
      smin[threadIdx.x] = make_float4(fminf(a.x, c.x), fminf(a.y, c.y), fminf(a.z, c.z), 0);
      float4 d = smax[threadIdx.x], e = smax[threadIdx.x + k];
      smax[threadIdx.x] = make_float4(fmaxf(d.x, e.x), fmaxf(d.y, e.y), fmaxf(d.z, e.z), 0);
    }
    __syncthreads();
  }
  if (threadIdx.x == 0) { bbox[cb * 2] = smin[0]; bbox[cb * 2 + 1] = smax[0]; }
}

__device__ __forceinline__ unsigned spread3(unsigned v) {
  v = (v * 0x00010001u) & 0xFF0000FFu;
  v = (v * 0x00000101u) & 0x0F00F00Fu;
  v = (v * 0x00000011u) & 0xC30C30C3u;
  v = (v * 0x00000005u) & 0x49249249u;
  return v;
}

// Morton-sort one (cloud,batch) in LDS (bitonic), write back in place, then
// per-chunk AABBs. Sort quality affects pruning SPEED only, not correctness.
__global__ __launch_bounds__(BLOCK) void sort_k(float4* __restrict__ pk1,
                                                float4* __restrict__ pk2,
                                                const float4* __restrict__ bbox,
                                                float4* __restrict__ chunkbox) {
  __shared__ float4 pts[Nn];                    // 32 KB
  __shared__ unsigned long long key[Nn];        // 16 KB
  const int cb = blockIdx.x, tid = threadIdx.x;
  float4* p = (cb < 16 ? pk1 : pk2) + (cb & 15) * Nn;
  float4 lo = bbox[cb * 2], hi = bbox[cb * 2 + 1];
  float sx = 255.0f / fmaxf(hi.x - lo.x, 1e-9f);
  float sy = 255.0f / fmaxf(hi.y - lo.y, 1e-9f);
  float sz = 255.0f / fmaxf(hi.z - lo.z, 1e-9f);
  for (int i = tid; i < Nn; i += BLOCK) {
    float4 v = p[i];
    pts[i] = v;
    unsigned qx = (unsigned)fminf(fmaxf((v.x - lo.x) * sx, 0.f), 255.f);
    unsigned qy = (unsigned)fminf(fmaxf((v.y - lo.y) * sy, 0.f), 255.f);
    unsigned qz = (unsigned)fminf(fmaxf((v.z - lo.z) * sz, 0.f), 255.f);
    unsigned m = spread3(qx) | (spread3(qy) << 1) | (spread3(qz) << 2);
    key[i] = ((unsigned long long)m << 11) | (unsigned long long)i;
  }
  __syncthreads();
  for (int k = 2; k <= Nn; k <<= 1)
    for (int j = k >> 1; j > 0; j >>= 1) {
      for (int t = tid; t < Nn / 2; t += BLOCK) {
        int i = ((t & ~(j - 1)) << 1) | (t & (j - 1));
        int ixj = i | j;
        bool up = ((i & k) == 0);
        unsigned long long a = key[i], bq = key[ixj];
        if ((a > bq) == up) { key[i] = bq; key[ixj] = a; }
      }
      __syncthreads();
    }
  float4 g[Nn / BLOCK];
  #pragma unroll
  for (int c = 0; c < Nn / BLOCK; ++c)
    g[c] = pts[(unsigned)(key[tid + c * BLOCK] & 2047ull)];
  __syncthreads();
  #pragma unroll
  for (int c = 0; c < Nn / BLOCK; ++c) {
    pts[tid + c * BLOCK] = g[c];
    p[tid + c * BLOCK]   = g[c];
  }
  __syncthreads();
  const int lane = tid & 63, wid = tid >> 6;
  for (int c = wid; c < NCH; c += 4) {
    float4 v = pts[c * 64 + lane];
    float mnx = v.x, mny = v.y, mnz = v.z, mxx = v.x, mxy = v.y, mxz = v.z;
    #pragma unroll
    for (int off = 1; off < 64; off <<= 1) {
      mnx = fminf(mnx, __shfl_xor(mnx, off)); mny = fminf(mny, __shfl_xor(mny, off));
      mnz = fminf(mnz, __shfl_xor(mnz, off)); mxx = fmaxf(mxx, __shfl_xor(mxx, off));
      mxy = fmaxf(mxy, __shfl_xor(mxy, off)); mxz = fmaxf(mxz, __shfl_xor(mxz, off));
    }
    if (lane == 0) {
      chunkbox[(cb * NCH + c) * 2]     = make_float4(mnx, mny, mnz, 0);
      chunkbox[(cb * NCH + c) * 2 + 1] = make_float4(mxx, mxy, mxz, 0);
    }
  }
}

__device__ __forceinline__ bool conv_check(const unsigned* chk, int tid, float* convm) {
  if (tid < 32) {
    float v = __uint_as_float(__hip_atomic_load(
        chk + (tid >> 1) * SLOTSTRIDE + (tid & 1),
        __ATOMIC_RELAXED, __HIP_MEMORY_SCOPE_AGENT));
    #pragma unroll
    for (int off = 16; off >= 1; off >>= 1) v = fmaxf(v, __shfl_xor(v, off));
    if (tid == 0) *convm = v;
  }
  __syncthreads();
  return *convm < TOLf;
}

// it=0 half-steps: full-scan online-max (no prior shift); also writes chunkmax.
__global__ __launch_bounds__(BLOCK, 8) void sink_pass(
    const float4* __restrict__ pkc, float4* __restrict__ pkr,
    float* __restrict__ potr, unsigned* slotbase, int uvsel,
    float* __restrict__ cmout) {
  __shared__ float red[4], redw[4];
  const int tid = threadIdx.x, lane = tid & 63, wid = tid >> 6;
  const int b = blockIdx.x >> 7, sub = blockIdx.x & 127;
  const float4* PC = pkc + b * Mm;
  float4*       PRq = pkr + b * Nn;
  float*        QR  = potr + b * Nn;

  const int base_n = sub * RPB + wid * RW;
  float qx[RW], qy[RW], qz[RW], rm[RW], ss[RW];
  #pragma unroll
  for (int r = 0; r < RW; ++r) {
    float4 q = PRq[base_n + r];
    qx[r] = q.x; qy[r] = q.y; qz[r] = q.z;
    rm[r] = -3.0e38f; ss[r] = 0.0f;
  }

  const float4* p = PC + lane;
  #pragma unroll 2
  for (int j = 0; j < 32; j += 4) {
    float4 f0 = p[(j + 0) * 64];
    float4 f1 = p[(j + 1) * 64];
    float4 f2 = p[(j + 2) * 64];
    float4 f3 = p[(j + 3) * 64];
    #pragma unroll
    for (int r = 0; r < RW; ++r) {
      float dx0 = f0.x - qx[r], dy0 = f0.y - qy[r], dz0 = f0.z - qz[r];
      float dx1 = f1.x - qx[r], dy1 = f1.y - qy[r], dz1 = f1.z - qz[r];
      float dx2 = f2.x - qx[r], dy2 = f2.y - qy[r], dz2 = f2.z - qz[r];
      float dx3 = f3.x - qx[r], dy3 = f3.y - qy[r], dz3 = f3.z - qz[r];
      float d0 = fmaf(dz0, dz0, fmaf(dy0, dy0, dx0 * dx0));
      float d1 = fmaf(dz1, dz1, fmaf(dy1, dy1, dx1 * dx1));
      float d2 = fmaf(dz2, dz2, fmaf(dy2, dy2, dx2 * dx2));
      float d3 = fmaf(dz3, dz3, fmaf(dy3, dy3, dx3 * dx3));
      float y0 = fmaf(__builtin_amdgcn_sqrtf(d0), -C2f, f0.w);
      float y1 = fmaf(__builtin_amdgcn_sqrtf(d1), -C2f, f1.w);
      float y2 = fmaf(__builtin_amdgcn_sqrtf(d2), -C2f, f2.w);
      float y3 = fmaf(__builtin_amdgcn_sqrtf(d3), -C2f, f3.w);
      float pm = fmaxf(fmaxf(y0, y1), fmaxf(y2, y3));
      float nm = fmaxf(rm[r], pm);
      float e  = (ex2(y0 - nm) + ex2(y1 - nm)) + (ex2(y2 - nm) + ex2(y3 - nm));
      ss[r] = fmaf(ss[r], ex2(rm[r] - nm), e);
      rm[r] = nm;
    }
  }

  const float log_ab = logf(1.0f / 2048.0f + 1e-8f);
  float* PRw = (float*)(PRq);
  float dmax = 0.0f, wmax = -3.0e38f;
  #pragma unroll
  for (int r = 0; r < RW; ++r) {
    float gm = rm[r];
    #pragma unroll
    for (int off = 1; off < 64; off <<= 1) gm = fmaxf(gm, __shfl_xor(gm, off));
    float sc = ss[r] * ex2(rm[r] - gm);
    #pragma unroll
    for (int off = 1; off < 64; off <<= 1) sc += __shfl_xor(sc, off);
    float lse = (gm + __builtin_amdgcn_logf(sc)) * LN2f;
    float pnew = EPSf * (log_ab - lse);
    if (lane == 0) {
      int n = base_n + r;
      dmax = fmaxf(dmax, fabsf(pnew - QR[n]));
      QR[n] = pnew;
      PRw[4 * n + 3] = pnew * C2f;
      wmax = fmaxf(wmax, pnew * C2f);
    }
  }
  if (lane == 0) { red[wid] = dmax; redw[wid] = wmax; }
  __syncthreads();
  if (tid == 0) {
    float m = fmaxf(fmaxf(red[0], red[1]), fmaxf(red[2], red[3]));
    atomicMax(slotbase + b * SLOTSTRIDE + uvsel, __float_as_uint(m));
    cmout[(b * NCH + (sub >> 2)) * 4 + (sub & 3)] =
        fmaxf(fmaxf(redw[0], redw[1]), fmaxf(redw[2], redw[3]));
  }
}

// it>=1: fixed-shift LSE + chunk pruning. Keep chunk c iff
// cmw_c - C2*dlow - K_r > -THR for any of the wave's 4 rows; the dominant
// chunk provably survives while drift*C2 < THR-11.
__global__ __launch_bounds__(BLOCK, 8) void sink_fast(
    const float4* __restrict__ pkc, float4* __restrict__ pkr,
    float* __restrict__ potr, unsigned* slotbase, const unsigned* chk, int uvsel,
    const float4* __restrict__ cbox_cols, const float* __restrict__ cm_cols,
    float* __restrict__ cmout, float thrAdd) {
  __shared__ float red[4], redw[4];
  __shared__ float convm;
  const int tid = threadIdx.x, lane = tid & 63, wid = tid >> 6;
  if (conv_check(chk, tid, &convm)) return;
  const int b = blockIdx.x >> 7, sub = blockIdx.x & 127;
  const float4* PC = pkc + b * Mm;
  float4*       PRq = pkr + b * Nn;
  float*        QR  = potr + b * Nn;

  const float log_ab = logf(1.0f / 2048.0f + 1e-8f);
  const float log2ab = log_ab * L2Ef;
  const float invC2 = 1.0f / C2f;

  const int base_n = sub * RPB + wid * RW;
  float qx[RW], qy[RW], qz[RW], K[RW], up[RW], s[RW];
  #pragma unroll
  for (int r = 0; r < RW; ++r) {
    float4 q = PRq[base_n + r];                 // wave-uniform
    qx[r] = q.x; qy[r] = q.y; qz[r] = q.z;
    up[r] = QR[base_n + r];
    K[r]  = log2ab - q.w;
    s[r]  = 0.0f;
  }

  // chunk screening: lanes 0..31 test chunk=lane for each row; union mask.
  float4 clo = make_float4(0, 0, 0, 0), chi = clo;
  float cmw = -3.0e38f;
  if (lane < 32) {
    clo = cbox_cols[(b * NCH + lane) * 2];
    chi = cbox_cols[(b * NCH + lane) * 2 + 1];
    float4 c4 = ((const float4*)cm_cols)[b * NCH + lane];
    cmw = fmaxf(fmaxf(c4.x, c4.y), fmaxf(c4.z, c4.w));
  }
  unsigned msk = 0;
  #pragma unroll
  for (int r = 0; r < RW; ++r) {
    float thr = (cmw - K[r] + thrAdd) * invC2;
    float ax = fmaxf(fmaxf(clo.x - qx[r], qx[r] - chi.x), 0.0f);
    float ay = fmaxf(fmaxf(clo.y - qy[r], qy[r] - chi.y), 0.0f);
    float az = fmaxf(fmaxf(clo.z - qz[r], qz[r] - chi.z), 0.0f);
    float d2low = fmaf(az, az, fmaf(ay, ay, ax * ax));
    bool keep = (lane < 32) && (thr > 0.0f) && (d2low <= thr * thr);
    msk |= (unsigned)(__ballot(keep) & 0xFFFFFFFFull);
  }

  const float4* p = PC + lane;
  if (msk) {
    int j = __builtin_ctz(msk); msk &= msk - 1;
    float4 f = p[j * 64];
    for (;;) {
      float4 fn; bool more = (msk != 0);
      if (more) { int jn = __builtin_ctz(msk); msk &= msk - 1; fn = p[jn * 64]; }
      #pragma unroll
      for (int r = 0; r < RW; ++r) {
        float dx = f.x - qx[r], dy = f.y - qy[r], dz = f.z - qz[r];
        float d2 = fmaf(dz, dz, fmaf(dy, dy, dx * dx));
        s[r] += ex2(fmaf(__builtin_amdgcn_sqrtf(d2), -C2f, f.w - K[r]));
      }
      if (!more) break;
      f = fn;
    }
  }

  float* PRw = (float*)(PRq);
  float dmax = 0.0f, wmax = -3.0e38f;
  #pragma unroll
  for (int r = 0; r < RW; ++r) {
    float sv = s[r];
    #pragma unroll
    for (int off = 1; off < 64; off <<= 1) sv += __shfl_xor(sv, off);
    sv = fmaxf(sv, 1e-37f);                     // never log(0)
    float lse = (K[r] + __builtin_amdgcn_logf(sv)) * LN2f;
    float pnew = EPSf * (log_ab - lse);
    if (lane == 0) {
      int n = base_n + r;
      dmax = fmaxf(dmax, fabsf(pnew - up[r]));
      QR[n] = pnew;
      PRw[4 * n + 3] = pnew * C2f;
      wmax = fmaxf(wmax, pnew * C2f);
    }
  }
  if (lane == 0) { red[wid] = dmax; redw[wid] = wmax; }
  __syncthreads();
  if (tid == 0) {
    float m = fmaxf(fmaxf(red[0], red[1]), fmaxf(red[2], red[3]));
    atomicMax(slotbase + b * SLOTSTRIDE + uvsel, __float_as_uint(m));
    cmout[(b * NCH + (sub >> 2)) * 4 + (sub & 3)] =
        fmaxf(fmaxf(redw[0], redw[1]), fmaxf(redw[2], redw[3]));
  }
}

// full-scan final contraction (1 dispatch; not worth pruning)
__global__ __launch_bounds__(BLOCK, 8) void final_emd(
    const float4* __restrict__ pk1, const float4* __restrict__ pk2,
    const float* __restrict__ U, float* __restrict__ part) {
  __shared__ float red[4];
  const int tid = threadIdx.x, lane = tid & 63, wid = tid >> 6;
  const int b = blockIdx.x >> 7, sub = blockIdx.x & 127;
  const float4* PC = pk2 + b * Mm;
  const float4* PRq = pk1 + b * Nn;

  const int base_n = sub * RPB + wid * RW;
  float qx[RW], qy[RW], qz[RW], uc[RW], ac[RW];
  #pragma unroll
  for (int r = 0; r < RW; ++r) {
    float4 q = PRq[base_n + r];
    qx[r] = q.x; qy[r] = q.y; qz[r] = q.z;
    uc[r] = U[b * Nn + base_n + r] * C2f;
    ac[r] = 0.0f;
  }

  const float4* p = PC + lane;
  #pragma unroll 2
  for (int j = 0; j < 32; j += 4) {
    float4 f0 = p[(j + 0) * 64];
    float4 f1 = p[(j + 1) * 64];
    float4 f2 = p[(j + 2) * 64];
    float4 f3 = p[(j + 3) * 64];
    #pragma unroll
    for (int r = 0; r < RW; ++r) {
      float dx0 = f0.x - qx[r], dy0 = f0.y - qy[r], dz0 = f0.z - qz[r];
      float dx1 = f1.x - qx[r], dy1 = f1.y - qy[r], dz1 = f1.z - qz[r];
      float dx2 = f2.x - qx[r], dy2 = f2.y - qy[r], dz2 = f2.z - qz[r];
      float dx3 = f3.x - qx[r], dy3 = f3.y - qy[r], dz3 = f3.z - qz[r];
      float e0 = fmaf(dz0, dz0, fmaf(dy0, dy0, dx0 * dx0));
      float e1 = fmaf(dz1, dz1, fmaf(dy1, dy1, dx1 * dx1));
      float e2 = fmaf(dz2, dz2, fmaf(dy2, dy2, dx2 * dx2));
      float e3 = fmaf(dz3, dz3, fmaf(dy3, dy3, dx3 * dx3));
      float t0 = __builtin_amdgcn_sqrtf(e0);
      float t1 = __builtin_amdgcn_sqrtf(e1);
      float t2 = __builtin_amdgcn_sqrtf(e2);
      float t3 = __builtin_amdgcn_sqrtf(e3);
      ac[r] = fmaf(ex2(fmaf(t0, -C2f, f0.w) + uc[r]), t0, ac[r]);
      ac[r] = fmaf(ex2(fmaf(t1, -C2f, f1.w) + uc[r]), t1, ac[r]);
      ac[r] = fmaf(ex2(fmaf(t2, -C2f, f2.w) + uc[r]), t2, ac[r]);
      ac[r] = fmaf(ex2(fmaf(t3, -C2f, f3.w) + uc[r]), t3, ac[r]);
    }
  }
  float acc = 0.0f;
  #pragma unroll
  for (int r = 0; r < RW; ++r) acc += ac[r];
  #pragma unroll
  for (int off = 1; off < 64; off <<= 1) acc += __shfl_xor(acc, off);
  if (lane == 0) red[wid] = acc;
  __syncthreads();
  if (tid == 0) part[blockIdx.x] = (red[0] + red[1]) + (red[2] + red[3]);
}

__global__ __launch_bounds__(BLOCK) void write_out(const float* __restrict__ part,
                                                   float* __restrict__ out) {
  __shared__ double sd[BLOCK];
  int t = threadIdx.x;
  double s = 0.0;
  for (int i = t; i < GRID; i += BLOCK) s += (double)part[i];
  sd[t] = s;
  __syncthreads();
  for (int k = BLOCK / 2; k > 0; k >>= 1) {
    if (t < k) sd[t] += sd[t + k];
    __syncthreads();
  }
  if (t == 0) out[0] = (float)(sd[0] / (double)Bb);
}

extern "C" void kernel_launch(void* const* d_in, const int* in_sizes, int n_in,
                              void* d_out, int out_size, void* d_ws, size_t ws_size,
                              hipStream_t stream) {
  (void)in_sizes; (void)n_in; (void)out_size; (void)ws_size;
  const float* p1 = (const float*)d_in[0];
  const float* p2 = (const float*)d_in[1];
  char* ws = (char*)d_ws;
  float4*   pk1   = (float4*)(ws + 0);          // 524288
  float4*   pk2   = (float4*)(ws + 524288);     // 524288
  float*    U     = (float*)(ws + 1048576);     // 131072
  float*    V     = (float*)(ws + 1179648);     // 131072
  unsigned* slots = (unsigned*)(ws + 1310720);  // 102400
  float*    part  = (float*)(ws + 1413120);     // 8192
  float4*   bbox  = (float4*)(ws + 1421312);    // 1024
  float4*   cbox  = (float4*)(ws + 1422336);    // 32768
  float*    cm    = (float*)(ws + 1455104);     // 16384
  float4*   cbox1 = cbox;                       // cloud1 = cb 0..15
  float4*   cbox2 = cbox + 16 * NCH * 2;
  float*    cm1   = cm;
  float*    cm2   = cm + 16 * NCH * 4;

  const int npts = Bb * Nn;
  pack_pts<<<(npts + BLOCK - 1) / BLOCK, BLOCK, 0, stream>>>(p1, pk1, npts);
  pack_pts<<<(npts + BLOCK - 1) / BLOCK, BLOCK, 0, stream>>>(p2, pk2, npts);
  bbox_k<<<32, BLOCK, 0, stream>>>(pk1, pk2, bbox);
  sort_k<<<32, BLOCK, 0, stream>>>(pk1, pk2, bbox, cbox);
  const int nwords = 2 * Bb * Nn + MAXIT * Bb * SLOTSTRIDE;
  init_ws<<<(nwords + BLOCK - 1) / BLOCK, BLOCK, 0, stream>>>((unsigned*)(ws + 1048576), nwords);

  // it = 0: full-scan online-max (also seeds chunkmax)
  sink_pass<<<GRID, BLOCK, 0, stream>>>(pk2, pk1, U, slots, 0, cm1);
  sink_pass<<<GRID, BLOCK, 0, stream>>>(pk1, pk2, V, slots, 1, cm2);
  // it = 1..99: pruned fixed-shift path
  for (int it = 1; it < MAXIT; ++it) {
    unsigned*       sl  = slots + it * Bb * SLOTSTRIDE;
    const unsigned* chk = slots + (it - 1) * Bb * SLOTSTRIDE;
    float thr = (it < 4) ? 120.0f : 80.0f;
    sink_fast<<<GRID, BLOCK, 0, stream>>>(pk2, pk1, U, sl, chk, 0, cbox2, cm2, cm1, thr);
    sink_fast<<<GRID, BLOCK, 0, stream>>>(pk1, pk2, V, sl, chk, 1, cbox1, cm1, cm2, thr);
  }

  final_emd<<<GRID, BLOCK, 0, stream>>>(pk1, pk2, U, part);
  write_out<<<1, BLOCK, 0, stream>>>(part, (float*)d_out);
}